// Round 1
// baseline (261.152 us; speedup 1.0000x reference)
//
#include <hip/hip_runtime.h>

typedef _Float16 half_t;
typedef _Float16 h8 __attribute__((ext_vector_type(8)));
typedef _Float16 h4 __attribute__((ext_vector_type(4)));
typedef float f32x4 __attribute__((ext_vector_type(4)));

#define S_LEN 2048
#define DMODEL 1024
#define NHEAD 16
#define HDK 64
#define NB 2
#define MROWS (NB * S_LEN)  // 4096

// ---------------------------------------------------------------------------
// async global->LDS, 16B per lane. LDS dest = wave-uniform base + lane*16.
__device__ __forceinline__ void gload_lds16(const void* g, void* l) {
  __builtin_amdgcn_global_load_lds(
      (const __attribute__((address_space(1))) unsigned int*)g,
      (__attribute__((address_space(3))) unsigned int*)l, 16, 0, 0);
}

// XOR swizzle: spreads stride-128B row reads across LDS banks (G4).
__device__ __forceinline__ int swz(int row, int colByte) {
  return row * 128 + (colByte ^ ((row & 7) << 4));
}

// ---------------------------------------------------------------------------
__global__ __launch_bounds__(256) void cvt_kernel(const float* __restrict__ in,
                                                  half_t* __restrict__ out, int n4) {
  int i = blockIdx.x * 256 + threadIdx.x;
  if (i < n4) {
    float4 v = ((const float4*)in)[i];
    h4 o;
    o[0] = (half_t)v.x; o[1] = (half_t)v.y; o[2] = (half_t)v.z; o[3] = (half_t)v.w;
    ((h4*)out)[i] = o;
  }
}

__global__ __launch_bounds__(256) void pack_mask_kernel(const int* __restrict__ mask,
                                                        unsigned int* __restrict__ mbits) {
  int i = blockIdx.x * 256 + threadIdx.x;  // over S*S, exact grid
  int v = mask[i];
  unsigned long long b = __ballot(v != 0);
  int lane = threadIdx.x & 63;
  if (lane == 0)       mbits[i >> 5] = (unsigned int)b;
  else if (lane == 32) mbits[i >> 5] = (unsigned int)(b >> 32);
}

// ---------------------------------------------------------------------------
// NT GEMM: C[m][n] = sum_k A[m][k] * W[n][k] (+ bias[n]); M=4096, N=K=1024.
// 128x128 tile, BK=32, 4 waves each 64x64, 16x16x32 f16 MFMA (m97 structure).
// EPI=0: out = f16, layout [B,H,S,64], y=(acc+bias)*scale (scale=1/8 for Q).
// EPI=1: out = f32 row-major [M][N], y=acc+bias.
template <int EPI>
__global__ __launch_bounds__(256) void gemm_kernel(
    const half_t* __restrict__ A0, const half_t* __restrict__ A1, const half_t* __restrict__ A2,
    const half_t* __restrict__ W0, const half_t* __restrict__ W1, const half_t* __restrict__ W2,
    const float* __restrict__ b0, const float* __restrict__ b1, const float* __restrict__ b2,
    void* o0, void* o1, void* o2) {
  const half_t* A; const half_t* W; const float* bias; void* out; float scale;
  if (blockIdx.z == 0)      { A = A0; W = W0; bias = b0; out = o0; scale = (EPI == 0) ? 0.125f : 1.0f; }
  else if (blockIdx.z == 1) { A = A1; W = W1; bias = b1; out = o1; scale = 1.0f; }
  else                      { A = A2; W = W2; bias = b2; out = o2; scale = 1.0f; }

  __shared__ half_t As[128 * 32];
  __shared__ half_t Bs[128 * 32];
  const int tid = threadIdx.x;
  const int w = tid >> 6, lane = tid & 63;
  const int wm = w >> 1, wn = w & 1;
  const int bm = blockIdx.x, bn = blockIdx.y;
  const int crow = lane >> 2;       // 0..15 (row within 16-row chunk)
  const int ck = (lane & 3) * 8;    // k element offset of this lane's 16B

  f32x4 acc[4][4] = {};

  const half_t* Ag0 = A + (size_t)(bm * 128 + w * 16 + crow) * DMODEL + ck;
  const half_t* Ag1 = Ag0 + 64 * DMODEL;
  const half_t* Wg0 = W + (size_t)(bn * 128 + w * 16 + crow) * DMODEL + ck;
  const half_t* Wg1 = Wg0 + 64 * DMODEL;
  half_t* lA0 = As + w * 512;       // 512 f16 = 1 KiB chunk per wave
  half_t* lA1 = As + (w + 4) * 512;
  half_t* lB0 = Bs + w * 512;
  half_t* lB1 = Bs + (w + 4) * 512;

  for (int kt = 0; kt < DMODEL; kt += 32) {
    __syncthreads();  // previous iter's frag reads done
    gload_lds16(Ag0 + kt, lA0);
    gload_lds16(Ag1 + kt, lA1);
    gload_lds16(Wg0 + kt, lB0);
    gload_lds16(Wg1 + kt, lB1);
    __syncthreads();  // compiler drains vmcnt before barrier

    h8 af[4], bf[4];
    const int rr = lane & 15;
    const int kk = (lane >> 4) * 8;
#pragma unroll
    for (int i = 0; i < 4; ++i)
      af[i] = *(const h8*)(As + (wm * 64 + i * 16 + rr) * 32 + kk);
#pragma unroll
    for (int j = 0; j < 4; ++j)
      bf[j] = *(const h8*)(Bs + (wn * 64 + j * 16 + rr) * 32 + kk);
#pragma unroll
    for (int i = 0; i < 4; ++i)
#pragma unroll
      for (int j = 0; j < 4; ++j)
        acc[i][j] = __builtin_amdgcn_mfma_f32_16x16x32_f16(af[i], bf[j], acc[i][j], 0, 0, 0);
  }

  // epilogue: C row = (lane>>4)*4 + jj, col = lane&15 (per 16x16 fragment)
  const int r0 = bm * 128 + wm * 64;
  const int c0 = bn * 128 + wn * 64;
#pragma unroll
  for (int j = 0; j < 4; ++j) {
    int col = c0 + j * 16 + (lane & 15);
    float bc = bias[col];
#pragma unroll
    for (int i = 0; i < 4; ++i) {
#pragma unroll
      for (int jj = 0; jj < 4; ++jj) {
        int row = r0 + i * 16 + (lane >> 4) * 4 + jj;
        float val = acc[i][j][jj] + bc;
        if (EPI == 0) {
          int b = row >> 11, s = row & (S_LEN - 1);
          int hh = col >> 6, dk = col & 63;
          ((half_t*)out)[(((size_t)(b * NHEAD + hh)) * S_LEN + s) * HDK + dk] =
              (half_t)(val * scale);
        } else {
          ((float*)out)[(size_t)row * DMODEL + col] = val;
        }
      }
    }
  }
}

// ---------------------------------------------------------------------------
// Flash attention. Block = 4 waves, 64 Q rows (16/wave), KV tiles of 64.
// Q pre-scaled by 1/8. Mask quirk: masked scores := 1e-9 BEFORE max/softmax.
__global__ __launch_bounds__(256) void attn_kernel(
    const half_t* __restrict__ Qp, const half_t* __restrict__ Kp,
    const half_t* __restrict__ Vp, const unsigned int* __restrict__ mbits,
    half_t* __restrict__ AO) {
  __shared__ half_t QPs[64 * 64];  // Q tile, then reused as P tile
  __shared__ half_t Ks[64 * 64];   // K tile [kcol][dk], swizzled
  __shared__ half_t Vs[64 * 64];   // V tile TRANSPOSED [dk][kb], swizzled

  const int tid = threadIdx.x, w = tid >> 6, lane = tid & 63;
  const int qt = blockIdx.x, bh = blockIdx.y;
  const int b = bh >> 4, h = bh & 15;
  const half_t* Qb = Qp + (size_t)bh * S_LEN * HDK;
  const half_t* Kb = Kp + (size_t)bh * S_LEN * HDK;
  const half_t* Vb = Vp + (size_t)bh * S_LEN * HDK;
  const int g = lane >> 4;

  // stage Q tile (swizzled)
#pragma unroll
  for (int p = 0; p < 2; ++p) {
    int idx = (p * 256 + tid) * 8;
    int row = idx >> 6, col = idx & 63;
    h8 v = *(const h8*)(Qb + (size_t)(qt * 64 + row) * HDK + col);
    *(h8*)((char*)QPs + swz(row, col * 2)) = v;
  }
  __syncthreads();

  // hoist Q fragments (constant across KV loop); frees QPs for P reuse
  h8 qf[2];
  {
    int row = w * 16 + (lane & 15);
#pragma unroll
    for (int ks = 0; ks < 2; ++ks) {
      int k0 = ks * 32 + g * 8;
      qf[ks] = *(const h8*)((char*)QPs + swz(row, k0 * 2));
    }
  }

  f32x4 acc[4] = {};        // out [16 q][64 dk]: 4 n-frags
  float m_run[4], l_run[4]; // per C-row (jj) online stats, replicated in 16-lane group
#pragma unroll
  for (int j = 0; j < 4; ++j) { m_run[j] = -1e30f; l_run[j] = 0.f; }

  for (int kv = 0; kv < S_LEN / 64; ++kv) {
    __syncthreads();  // prev iter's Ks/Vs reads complete (also covers qf reads, iter 0)
    // stage K (swizzled) and V (transposed + swizzled)
#pragma unroll
    for (int p = 0; p < 2; ++p) {
      int idx = (p * 256 + tid) * 8;
      int row = idx >> 6, col = idx & 63;
      h8 v = *(const h8*)(Kb + (size_t)(kv * 64 + row) * HDK + col);
      *(h8*)((char*)Ks + swz(row, col * 2)) = v;
    }
#pragma unroll
    for (int p = 0; p < 2; ++p) {
      int idx = (p * 256 + tid) * 8;
      int row = idx >> 6, col = idx & 63;  // row = kb, col = dk0
      h8 v = *(const h8*)(Vb + (size_t)(kv * 64 + row) * HDK + col);
#pragma unroll
      for (int e = 0; e < 8; ++e)
        *(half_t*)((char*)Vs + swz(col + e, row * 2)) = v[e];
    }
    __syncthreads();

    // scores S = Qs * K^T : per wave [16 q][64 k], 4 n-frags x 2 k-steps
    f32x4 sc[4] = {};
#pragma unroll
    for (int n = 0; n < 4; ++n) {
#pragma unroll
      for (int ks = 0; ks < 2; ++ks) {
        int krow = n * 16 + (lane & 15);
        int k0 = ks * 32 + g * 8;
        h8 kf = *(const h8*)((char*)Ks + swz(krow, k0 * 2));
        sc[n] = __builtin_amdgcn_mfma_f32_16x16x32_f16(qf[ks], kf, sc[n], 0, 0, 0);
      }
    }

    // mask (-> 1e-9) + row max
    float pv[4][4];  // [n][jj]
    float rmax[4];
#pragma unroll
    for (int j = 0; j < 4; ++j) {
      int qrow = qt * 64 + w * 16 + g * 4 + j;
      unsigned int mw0 = mbits[qrow * (S_LEN / 32) + kv * 2 + 0];
      unsigned int mw1 = mbits[qrow * (S_LEN / 32) + kv * 2 + 1];
      float mx = -1e30f;
#pragma unroll
      for (int n = 0; n < 4; ++n) {
        unsigned int mword = (n < 2) ? mw0 : mw1;
        int bit = ((n & 1) << 4) | (lane & 15);
        float s = sc[n][j];
        s = ((mword >> bit) & 1u) ? s : 1e-9f;
        pv[n][j] = s;
        mx = fmaxf(mx, s);
      }
      mx = fmaxf(mx, __shfl_xor(mx, 1));
      mx = fmaxf(mx, __shfl_xor(mx, 2));
      mx = fmaxf(mx, __shfl_xor(mx, 4));
      mx = fmaxf(mx, __shfl_xor(mx, 8));
      rmax[j] = mx;
    }

    // online softmax update
    float scl[4];
#pragma unroll
    for (int j = 0; j < 4; ++j) {
      float mnew = fmaxf(m_run[j], rmax[j]);
      scl[j] = __expf(m_run[j] - mnew);
      float rs = 0.f;
#pragma unroll
      for (int n = 0; n < 4; ++n) {
        float p = __expf(pv[n][j] - mnew);
        pv[n][j] = p;
        rs += p;
      }
      rs += __shfl_xor(rs, 1);
      rs += __shfl_xor(rs, 2);
      rs += __shfl_xor(rs, 4);
      rs += __shfl_xor(rs, 8);
      l_run[j] = l_run[j] * scl[j] + rs;
      m_run[j] = mnew;
    }
#pragma unroll
    for (int n = 0; n < 4; ++n)
#pragma unroll
      for (int j = 0; j < 4; ++j) acc[n][j] *= scl[j];

    // write P tile (wave-local rows; QPs reuse), f16 swizzled
#pragma unroll
    for (int j = 0; j < 4; ++j) {
      int prow = w * 16 + g * 4 + j;
#pragma unroll
      for (int n = 0; n < 4; ++n) {
        int pcol = n * 16 + (lane & 15);
        *(half_t*)((char*)QPs + swz(prow, pcol * 2)) = (half_t)pv[n][j];
      }
    }
    asm volatile("s_waitcnt lgkmcnt(0)" ::: "memory");  // P writes visible before reads

    // PV: out += P * V. A from P tile (own rows), B from transposed V tile.
#pragma unroll
    for (int ks = 0; ks < 2; ++ks) {
      int prow = w * 16 + (lane & 15);
      int k0 = ks * 32 + g * 8;
      h8 pa = *(const h8*)((char*)QPs + swz(prow, k0 * 2));
#pragma unroll
      for (int n = 0; n < 4; ++n) {
        int dkr = n * 16 + (lane & 15);
        h8 vb = *(const h8*)((char*)Vs + swz(dkr, k0 * 2));
        acc[n] = __builtin_amdgcn_mfma_f32_16x16x32_f16(pa, vb, acc[n], 0, 0, 0);
      }
    }
  }

  // epilogue: out/l -> AO [B, S, H*64] f16
#pragma unroll
  for (int n = 0; n < 4; ++n) {
    int col = h * 64 + n * 16 + (lane & 15);
#pragma unroll
    for (int j = 0; j < 4; ++j) {
      int qrow = qt * 64 + w * 16 + g * 4 + j;
      float o = acc[n][j] / l_run[j];
      AO[(size_t)(b * S_LEN + qrow) * DMODEL + col] = (half_t)o;
    }
  }
}

// ---------------------------------------------------------------------------
extern "C" void kernel_launch(void* const* d_in, const int* in_sizes, int n_in,
                              void* d_out, int out_size, void* d_ws, size_t ws_size,
                              hipStream_t stream) {
  const float* q    = (const float*)d_in[0];
  const float* k    = (const float*)d_in[1];
  const float* v    = (const float*)d_in[2];
  const int*   mask = (const int*)d_in[3];
  const float* wq_w = (const float*)d_in[4];
  const float* wq_b = (const float*)d_in[5];
  const float* wk_w = (const float*)d_in[6];
  const float* wk_b = (const float*)d_in[7];
  const float* wv_w = (const float*)d_in[8];
  const float* wv_b = (const float*)d_in[9];
  const float* wo_w = (const float*)d_in[10];
  const float* wo_b = (const float*)d_in[11];
  float* out = (float*)d_out;

  // ws layout (needs ~56.5 MiB)
  char* ws = (char*)d_ws;
  const size_t MB = (size_t)1 << 20;
  half_t* Xq = (half_t*)(ws + 0 * MB);   // 8 MiB [4096][1024] f16
  half_t* Xk = (half_t*)(ws + 8 * MB);
  half_t* Xv = (half_t*)(ws + 16 * MB);
  half_t* Wq = (half_t*)(ws + 24 * MB);  // 2 MiB each
  half_t* Wk = (half_t*)(ws + 26 * MB);
  half_t* Wv = (half_t*)(ws + 28 * MB);
  half_t* Wo = (half_t*)(ws + 30 * MB);
  half_t* Qp = (half_t*)(ws + 32 * MB);  // [B,H,S,64] f16, 8 MiB each
  half_t* Kp = (half_t*)(ws + 40 * MB);
  half_t* Vp = (half_t*)(ws + 48 * MB);
  unsigned int* mbits = (unsigned int*)(ws + 56 * MB);  // 512 KiB
  half_t* AO = Xq;  // Xq dead after projections; reuse for attention output

  const int n_x4 = MROWS * DMODEL / 4;   // 1,048,576
  const int n_w4 = DMODEL * DMODEL / 4;  // 262,144
  cvt_kernel<<<n_x4 / 256, 256, 0, stream>>>(q, Xq, n_x4);
  cvt_kernel<<<n_x4 / 256, 256, 0, stream>>>(k, Xk, n_x4);
  cvt_kernel<<<n_x4 / 256, 256, 0, stream>>>(v, Xv, n_x4);
  cvt_kernel<<<n_w4 / 256, 256, 0, stream>>>(wq_w, Wq, n_w4);
  cvt_kernel<<<n_w4 / 256, 256, 0, stream>>>(wk_w, Wk, n_w4);
  cvt_kernel<<<n_w4 / 256, 256, 0, stream>>>(wv_w, Wv, n_w4);
  cvt_kernel<<<n_w4 / 256, 256, 0, stream>>>(wo_w, Wo, n_w4);
  pack_mask_kernel<<<(S_LEN * S_LEN) / 256, 256, 0, stream>>>(mask, mbits);

  gemm_kernel<0><<<dim3(32, 8, 3), 256, 0, stream>>>(
      Xq, Xk, Xv, Wq, Wk, Wv, wq_b, wk_b, wv_b, (void*)Qp, (void*)Kp, (void*)Vp);
  attn_kernel<<<dim3(S_LEN / 64, NB * NHEAD), 256, 0, stream>>>(Qp, Kp, Vp, mbits, AO);
  gemm_kernel<1><<<dim3(32, 8, 1), 256, 0, stream>>>(
      AO, AO, AO, Wo, Wo, Wo, wo_b, wo_b, wo_b, (void*)out, (void*)out, (void*)out);

  (void)in_sizes; (void)n_in; (void)out_size; (void)ws_size;
}

// Round 2
// 212.492 us; speedup vs baseline: 1.2290x; 1.2290x over previous
//
#include <hip/hip_runtime.h>

typedef _Float16 half_t;
typedef _Float16 h8 __attribute__((ext_vector_type(8)));
typedef _Float16 h4 __attribute__((ext_vector_type(4)));
typedef _Float16 h2 __attribute__((ext_vector_type(2)));
typedef float f32x4 __attribute__((ext_vector_type(4)));
typedef float f32x16 __attribute__((ext_vector_type(16)));

#define S_LEN 2048
#define DMODEL 1024
#define NHEAD 16
#define HDK 64
#define NB 2
#define MROWS (NB * S_LEN)  // 4096

// ---------------------------------------------------------------------------
__device__ __forceinline__ void gload_lds16(const void* g, void* l) {
  __builtin_amdgcn_global_load_lds(
      (const __attribute__((address_space(1))) unsigned int*)g,
      (__attribute__((address_space(3))) unsigned int*)l, 16, 0, 0);
}

// ---------------------------------------------------------------------------
// Fused prologue: f32->f16 converts for q,k,v,4 weights + mask bit-pack.
__global__ __launch_bounds__(256) void pre_kernel(
    const float* __restrict__ q, const float* __restrict__ k, const float* __restrict__ v,
    const float* __restrict__ wq, const float* __restrict__ wk,
    const float* __restrict__ wv, const float* __restrict__ wo,
    const int* __restrict__ mask,
    half_t* Xq, half_t* Xk, half_t* Xv,
    half_t* Wq, half_t* Wk, half_t* Wv, half_t* Wo,
    unsigned int* mbits) {
  const int gid = blockIdx.x, tid = threadIdx.x;
  if (gid < 16384) {  // convert region: 4,194,304 float4s total
    int i = gid * 256 + tid;
    const float* src; half_t* dst; int off;
    if (i < 3145728) {  // q,k,v: 1M float4 each
      int rgn = i >> 20; off = i & 1048575;
      src = rgn == 0 ? q : rgn == 1 ? k : v;
      dst = rgn == 0 ? Xq : rgn == 1 ? Xk : Xv;
    } else {            // weights: 256K float4 each
      int j = i - 3145728;
      int rgn = j >> 18; off = j & 262143;
      src = rgn == 0 ? wq : rgn == 1 ? wk : rgn == 2 ? wv : wo;
      dst = rgn == 0 ? Wq : rgn == 1 ? Wk : rgn == 2 ? Wv : Wo;
    }
    float4 vv = ((const float4*)src)[off];
    h4 o;
    o[0] = (half_t)vv.x; o[1] = (half_t)vv.y; o[2] = (half_t)vv.z; o[3] = (half_t)vv.w;
    ((h4*)dst)[off] = o;
  } else {            // mask pack region: 4,194,304 ints
    int i = (gid - 16384) * 256 + tid;
    int mv = mask[i];
    unsigned long long bm = __ballot(mv != 0);
    int lane = tid & 63;
    if (lane == 0)       mbits[i >> 5] = (unsigned int)bm;
    else if (lane == 32) mbits[i >> 5] = (unsigned int)(bm >> 32);
  }
}

// ---------------------------------------------------------------------------
// NT GEMM: C[m][n] = sum_k A[m][k] * W[n][k] (+ bias[n]); M=4096, N=K=1024.
// EPI=0: f16 out; z=0 -> Q [B,H,S,64] scaled 1/8; z=1 -> K [B,H,S,64];
//        z=2 -> V TRANSPOSED [B,H,64,S].
// EPI=1: f32 row-major [M][N].
template <int EPI>
__global__ __launch_bounds__(256) void gemm_kernel(
    const half_t* __restrict__ A0, const half_t* __restrict__ A1, const half_t* __restrict__ A2,
    const half_t* __restrict__ W0, const half_t* __restrict__ W1, const half_t* __restrict__ W2,
    const float* __restrict__ b0, const float* __restrict__ b1, const float* __restrict__ b2,
    void* o0, void* o1, void* o2) {
  const half_t* A; const half_t* W; const float* bias; void* out; float scale;
  if (blockIdx.z == 0)      { A = A0; W = W0; bias = b0; out = o0; scale = (EPI == 0) ? 0.125f : 1.0f; }
  else if (blockIdx.z == 1) { A = A1; W = W1; bias = b1; out = o1; scale = 1.0f; }
  else                      { A = A2; W = W2; bias = b2; out = o2; scale = 1.0f; }

  __shared__ half_t As[128 * 32];
  __shared__ half_t Bs[128 * 32];
  const int tid = threadIdx.x;
  const int w = tid >> 6, lane = tid & 63;
  const int wm = w >> 1, wn = w & 1;
  const int bm = blockIdx.x, bn = blockIdx.y;
  const int crow = lane >> 2;
  const int ck = (lane & 3) * 8;

  f32x4 acc[4][4] = {};

  const half_t* Ag0 = A + (size_t)(bm * 128 + w * 16 + crow) * DMODEL + ck;
  const half_t* Ag1 = Ag0 + 64 * DMODEL;
  const half_t* Wg0 = W + (size_t)(bn * 128 + w * 16 + crow) * DMODEL + ck;
  const half_t* Wg1 = Wg0 + 64 * DMODEL;
  half_t* lA0 = As + w * 512;
  half_t* lA1 = As + (w + 4) * 512;
  half_t* lB0 = Bs + w * 512;
  half_t* lB1 = Bs + (w + 4) * 512;

  for (int kt = 0; kt < DMODEL; kt += 32) {
    __syncthreads();
    gload_lds16(Ag0 + kt, lA0);
    gload_lds16(Ag1 + kt, lA1);
    gload_lds16(Wg0 + kt, lB0);
    gload_lds16(Wg1 + kt, lB1);
    __syncthreads();

    h8 af[4], bf[4];
    const int rr = lane & 15;
    const int kk = (lane >> 4) * 8;
#pragma unroll
    for (int i = 0; i < 4; ++i)
      af[i] = *(const h8*)(As + (wm * 64 + i * 16 + rr) * 32 + kk);
#pragma unroll
    for (int j = 0; j < 4; ++j)
      bf[j] = *(const h8*)(Bs + (wn * 64 + j * 16 + rr) * 32 + kk);
#pragma unroll
    for (int i = 0; i < 4; ++i)
#pragma unroll
      for (int j = 0; j < 4; ++j)
        acc[i][j] = __builtin_amdgcn_mfma_f32_16x16x32_f16(af[i], bf[j], acc[i][j], 0, 0, 0);
  }

  const int r0 = bm * 128 + wm * 64;
  const int c0 = bn * 128 + wn * 64;
#pragma unroll
  for (int j = 0; j < 4; ++j) {
    int col = c0 + j * 16 + (lane & 15);
    float bc = bias[col];
#pragma unroll
    for (int i = 0; i < 4; ++i) {
#pragma unroll
      for (int jj = 0; jj < 4; ++jj) {
        int row = r0 + i * 16 + (lane >> 4) * 4 + jj;
        float val = acc[i][j][jj] + bc;
        if (EPI == 0) {
          int bb = row >> 11, s = row & (S_LEN - 1);
          int hh = col >> 6, dk = col & 63;
          if (blockIdx.z == 2) {  // V^T: [B,H,64,S]
            ((half_t*)out)[((size_t)((bb * NHEAD + hh) * HDK + dk)) * S_LEN + s] = (half_t)val;
          } else {
            ((half_t*)out)[(((size_t)(bb * NHEAD + hh)) * S_LEN + s) * HDK + dk] =
                (half_t)(val * scale);
          }
        } else {
          ((float*)out)[(size_t)row * DMODEL + col] = val;
        }
      }
    }
  }
}

// ---------------------------------------------------------------------------
// LDS-free flash attention, swapped QK^T, 32x32x16 MFMA.
// Per wave: 32 q rows. Per KV tile (64): sc[kb][q] = K·Q^T; lane holds
// q=lane&31, kb rows in regs (row=(r&3)+8*(r>>2)+4*(lane>>5)). Softmax is
// in-lane + one shfl_xor(32). P->f16 A... B-frag via pack+permlane32_swap.
__global__ __launch_bounds__(256, 2) void attn_kernel(
    const half_t* __restrict__ Qp, const half_t* __restrict__ Kp,
    const half_t* __restrict__ VTp, const unsigned int* __restrict__ mbits,
    half_t* __restrict__ AO) {
  const int tid = threadIdx.x, w = tid >> 6, lane = tid & 63;
  // XCD-locality decode: 4 heads per XCD (id&7 = bh>>2) -> 2MB K/V per L2.
  const int id = blockIdx.x;
  const int xcd = id & 7, rr = id >> 3;
  const int qt = rr & 15;
  const int bh = (xcd << 2) | (rr >> 4);
  const int b = bh >> 4, h = bh & 15;
  const int q32 = lane & 31, hi = lane >> 5;
  const int qbase = qt * 128 + w * 32;
  const half_t* Qb = Qp + (size_t)bh * (S_LEN * HDK);
  const half_t* Kb = Kp + (size_t)bh * (S_LEN * HDK);
  const half_t* VTb = VTp + (size_t)bh * (S_LEN * HDK);
  const unsigned int* mrow = mbits + (size_t)(qbase + q32) * (S_LEN / 32);

  h8 qf[4];
#pragma unroll
  for (int s = 0; s < 4; ++s)
    qf[s] = *(const h8*)(Qb + (size_t)(qbase + q32) * HDK + s * 16 + hi * 8);

  f32x16 acc0 = {}, acc1 = {};
  float m_run = -1e30f, l_run = 0.f;

  for (int kv = 0; kv < S_LEN / 64; ++kv) {
    const half_t* Kt = Kb + (size_t)kv * 64 * HDK;
    const half_t* Vt = VTb + kv * 64;

    f32x16 sc0 = {}, sc1 = {};
#pragma unroll
    for (int s = 0; s < 4; ++s) {
      h8 kf = *(const h8*)(Kt + (size_t)q32 * HDK + s * 16 + hi * 8);
      sc0 = __builtin_amdgcn_mfma_f32_32x32x16_f16(kf, qf[s], sc0, 0, 0, 0);
    }
#pragma unroll
    for (int s = 0; s < 4; ++s) {
      h8 kf = *(const h8*)(Kt + (size_t)(32 + q32) * HDK + s * 16 + hi * 8);
      sc1 = __builtin_amdgcn_mfma_f32_32x32x16_f16(kf, qf[s], sc1, 0, 0, 0);
    }

    // prefetch V fragments (consumed after softmax -> latency hidden)
    h8 vf0[4], vf1[4];
#pragma unroll
    for (int s = 0; s < 4; ++s) {
      vf0[s] = *(const h8*)(Vt + (size_t)q32 * S_LEN + s * 16 + hi * 8);
      vf1[s] = *(const h8*)(Vt + (size_t)(32 + q32) * S_LEN + s * 16 + hi * 8);
    }

    // mask (-> 1e-9 quirk) + row max
    unsigned int mw0 = mrow[kv * 2 + 0] >> (hi * 4);
    unsigned int mw1 = mrow[kv * 2 + 1] >> (hi * 4);
    float mx = -1e30f;
#pragma unroll
    for (int rg = 0; rg < 16; ++rg) {
      const int bit = (rg & 3) + 8 * (rg >> 2);
      float s0 = ((mw0 >> bit) & 1u) ? sc0[rg] : 1e-9f;
      float s1 = ((mw1 >> bit) & 1u) ? sc1[rg] : 1e-9f;
      sc0[rg] = s0; sc1[rg] = s1;
      mx = fmaxf(mx, fmaxf(s0, s1));
    }
    mx = fmaxf(mx, __shfl_xor(mx, 32));

    float mnew = fmaxf(m_run, mx);
    float scl = __expf(m_run - mnew);
    float rs = 0.f;
#pragma unroll
    for (int rg = 0; rg < 16; ++rg) {
      float p0 = __expf(sc0[rg] - mnew);
      float p1 = __expf(sc1[rg] - mnew);
      sc0[rg] = p0; sc1[rg] = p1;
      rs += p0 + p1;
    }
    rs += __shfl_xor(rs, 32);
    l_run = l_run * scl + rs;
    m_run = mnew;
#pragma unroll
    for (int rg = 0; rg < 16; ++rg) { acc0[rg] *= scl; acc1[rg] *= scl; }

    // P (f32, lane-local P^T) -> f16 B-fragments via pack + permlane32_swap
    h8 pb[4];
#pragma unroll
    for (int s = 0; s < 4; ++s) {
      f32x16& P = (s < 2) ? sc0 : sc1;
      const int rb = (s & 1) * 8;
      union { h2 h; unsigned int u; } c01, c23, c45, c67;
      c01.h[0] = (half_t)P[rb + 0]; c01.h[1] = (half_t)P[rb + 1];
      c23.h[0] = (half_t)P[rb + 2]; c23.h[1] = (half_t)P[rb + 3];
      c45.h[0] = (half_t)P[rb + 4]; c45.h[1] = (half_t)P[rb + 5];
      c67.h[0] = (half_t)P[rb + 6]; c67.h[1] = (half_t)P[rb + 7];
      auto rA = __builtin_amdgcn_permlane32_swap(c01.u, c45.u, false, false);
      auto rB = __builtin_amdgcn_permlane32_swap(c23.u, c67.u, false, false);
      union { unsigned int u[4]; h8 v; } bw;
      bw.u[0] = rA[0]; bw.u[1] = rB[0]; bw.u[2] = rA[1]; bw.u[3] = rB[1];
      pb[s] = bw.v;
    }

    // PV: acc[d][q] += V^T · P
#pragma unroll
    for (int s = 0; s < 4; ++s) {
      acc0 = __builtin_amdgcn_mfma_f32_32x32x16_f16(vf0[s], pb[s], acc0, 0, 0, 0);
      acc1 = __builtin_amdgcn_mfma_f32_32x32x16_f16(vf1[s], pb[s], acc1, 0, 0, 0);
    }
  }

  // epilogue: AO[b*S+q][h*64+d] = acc/l
  const float inv = 1.0f / l_run;
  const int qrow = qbase + q32;
  const size_t obase = (size_t)(b * S_LEN + qrow) * DMODEL + h * HDK;
#pragma unroll
  for (int rg = 0; rg < 16; ++rg) {
    const int d = (rg & 3) + 8 * (rg >> 2) + 4 * hi;
    AO[obase + d]      = (half_t)(acc0[rg] * inv);
    AO[obase + 32 + d] = (half_t)(acc1[rg] * inv);
  }
}

// ---------------------------------------------------------------------------
extern "C" void kernel_launch(void* const* d_in, const int* in_sizes, int n_in,
                              void* d_out, int out_size, void* d_ws, size_t ws_size,
                              hipStream_t stream) {
  const float* q    = (const float*)d_in[0];
  const float* k    = (const float*)d_in[1];
  const float* v    = (const float*)d_in[2];
  const int*   mask = (const int*)d_in[3];
  const float* wq_w = (const float*)d_in[4];
  const float* wq_b = (const float*)d_in[5];
  const float* wk_w = (const float*)d_in[6];
  const float* wk_b = (const float*)d_in[7];
  const float* wv_w = (const float*)d_in[8];
  const float* wv_b = (const float*)d_in[9];
  const float* wo_w = (const float*)d_in[10];
  const float* wo_b = (const float*)d_in[11];
  float* out = (float*)d_out;

  char* ws = (char*)d_ws;
  const size_t MB = (size_t)1 << 20;
  half_t* Xq = (half_t*)(ws + 0 * MB);
  half_t* Xk = (half_t*)(ws + 8 * MB);
  half_t* Xv = (half_t*)(ws + 16 * MB);
  half_t* Wq = (half_t*)(ws + 24 * MB);
  half_t* Wk = (half_t*)(ws + 26 * MB);
  half_t* Wv = (half_t*)(ws + 28 * MB);
  half_t* Wo = (half_t*)(ws + 30 * MB);
  half_t* Qp = (half_t*)(ws + 32 * MB);
  half_t* Kp = (half_t*)(ws + 40 * MB);
  half_t* VT = (half_t*)(ws + 48 * MB);
  unsigned int* mbits = (unsigned int*)(ws + 56 * MB);
  half_t* AO = Xq;  // Xq dead after projections

  pre_kernel<<<32768, 256, 0, stream>>>(q, k, v, wq_w, wk_w, wv_w, wo_w, mask,
                                        Xq, Xk, Xv, Wq, Wk, Wv, Wo, mbits);
  gemm_kernel<0><<<dim3(32, 8, 3), 256, 0, stream>>>(
      Xq, Xk, Xv, Wq, Wk, Wv, wq_b, wk_b, wv_b, (void*)Qp, (void*)Kp, (void*)VT);
  attn_kernel<<<512, 256, 0, stream>>>(Qp, Kp, VT, mbits, AO);
  gemm_kernel<1><<<dim3(32, 8, 1), 256, 0, stream>>>(
      AO, AO, AO, Wo, Wo, Wo, wo_b, wo_b, wo_b, (void*)out, (void*)out, (void*)out);

  (void)in_sizes; (void)n_in; (void)out_size; (void)ws_size;
}

// Round 3
// 159.577 us; speedup vs baseline: 1.6365x; 1.3316x over previous
//
#include <hip/hip_runtime.h>

typedef _Float16 half_t;
typedef _Float16 h8 __attribute__((ext_vector_type(8)));
typedef _Float16 h4 __attribute__((ext_vector_type(4)));
typedef _Float16 h2 __attribute__((ext_vector_type(2)));
typedef float f32x4 __attribute__((ext_vector_type(4)));
typedef float f32x16 __attribute__((ext_vector_type(16)));

#define S_LEN 2048
#define DMODEL 1024
#define NHEAD 16
#define HDK 64
#define NB 2
#define MROWS (NB * S_LEN)  // 4096
#define LOG2E 1.44269504089f

// ---------------------------------------------------------------------------
__device__ __forceinline__ void gload_lds16(const void* g, void* l) {
  __builtin_amdgcn_global_load_lds(
      (const __attribute__((address_space(1))) unsigned int*)g,
      (__attribute__((address_space(3))) unsigned int*)l, 16, 0, 0);
}

// v_exp_f32 computes 2^x natively (scores carry log2e folded in from Q scale)
__device__ __forceinline__ float fast_exp2(float x) {
  float r;
  asm("v_exp_f32 %0, %1" : "=v"(r) : "v"(x));
  return r;
}

// XOR swizzle for 128-byte LDS rows (G4 / m214 pattern)
__device__ __forceinline__ int swz(int row, int colByte) {
  return row * 128 + (colByte ^ ((row & 7) << 4));
}

// ---------------------------------------------------------------------------
// Fused prologue: f32->f16 converts for q,k,v,4 weights + mask bit-pack.
__global__ __launch_bounds__(256) void pre_kernel(
    const float* __restrict__ q, const float* __restrict__ k, const float* __restrict__ v,
    const float* __restrict__ wq, const float* __restrict__ wk,
    const float* __restrict__ wv, const float* __restrict__ wo,
    const int* __restrict__ mask,
    half_t* Xq, half_t* Xk, half_t* Xv,
    half_t* Wq, half_t* Wk, half_t* Wv, half_t* Wo,
    unsigned int* mbits) {
  const int gid = blockIdx.x, tid = threadIdx.x;
  if (gid < 16384) {
    int i = gid * 256 + tid;
    const float* src; half_t* dst; int off;
    if (i < 3145728) {
      int rgn = i >> 20; off = i & 1048575;
      src = rgn == 0 ? q : rgn == 1 ? k : v;
      dst = rgn == 0 ? Xq : rgn == 1 ? Xk : Xv;
    } else {
      int j = i - 3145728;
      int rgn = j >> 18; off = j & 262143;
      src = rgn == 0 ? wq : rgn == 1 ? wk : rgn == 2 ? wv : wo;
      dst = rgn == 0 ? Wq : rgn == 1 ? Wk : rgn == 2 ? Wv : Wo;
    }
    float4 vv = ((const float4*)src)[off];
    h4 o;
    o[0] = (half_t)vv.x; o[1] = (half_t)vv.y; o[2] = (half_t)vv.z; o[3] = (half_t)vv.w;
    ((h4*)dst)[off] = o;
  } else {
    int i = (gid - 16384) * 256 + tid;
    int mv = mask[i];
    unsigned long long bm = __ballot(mv != 0);
    int lane = tid & 63;
    if (lane == 0)       mbits[i >> 5] = (unsigned int)bm;
    else if (lane == 32) mbits[i >> 5] = (unsigned int)(bm >> 32);
  }
}

// ---------------------------------------------------------------------------
// NT GEMM (m97 structure). EPI=0: f16 out; z=0 -> Q [B,H,S,64] scaled by
// (1/8)*log2e (exp2 softmax downstream); z=1 -> K; z=2 -> V^T [B,H,64,S].
// EPI=1: f32 row-major [M][N].
template <int EPI>
__global__ __launch_bounds__(256) void gemm_kernel(
    const half_t* __restrict__ A0, const half_t* __restrict__ A1, const half_t* __restrict__ A2,
    const half_t* __restrict__ W0, const half_t* __restrict__ W1, const half_t* __restrict__ W2,
    const float* __restrict__ b0, const float* __restrict__ b1, const float* __restrict__ b2,
    void* o0, void* o1, void* o2) {
  const half_t* A; const half_t* W; const float* bias; void* out; float scale;
  if (blockIdx.z == 0)      { A = A0; W = W0; bias = b0; out = o0; scale = (EPI == 0) ? 0.125f * LOG2E : 1.0f; }
  else if (blockIdx.z == 1) { A = A1; W = W1; bias = b1; out = o1; scale = 1.0f; }
  else                      { A = A2; W = W2; bias = b2; out = o2; scale = 1.0f; }

  __shared__ half_t As[128 * 32];
  __shared__ half_t Bs[128 * 32];
  const int tid = threadIdx.x;
  const int w = tid >> 6, lane = tid & 63;
  const int wm = w >> 1, wn = w & 1;
  const int bm = blockIdx.x, bn = blockIdx.y;
  const int crow = lane >> 2;
  const int ck = (lane & 3) * 8;

  f32x4 acc[4][4] = {};

  const half_t* Ag0 = A + (size_t)(bm * 128 + w * 16 + crow) * DMODEL + ck;
  const half_t* Ag1 = Ag0 + 64 * DMODEL;
  const half_t* Wg0 = W + (size_t)(bn * 128 + w * 16 + crow) * DMODEL + ck;
  const half_t* Wg1 = Wg0 + 64 * DMODEL;
  half_t* lA0 = As + w * 512;
  half_t* lA1 = As + (w + 4) * 512;
  half_t* lB0 = Bs + w * 512;
  half_t* lB1 = Bs + (w + 4) * 512;

  for (int kt = 0; kt < DMODEL; kt += 32) {
    __syncthreads();
    gload_lds16(Ag0 + kt, lA0);
    gload_lds16(Ag1 + kt, lA1);
    gload_lds16(Wg0 + kt, lB0);
    gload_lds16(Wg1 + kt, lB1);
    __syncthreads();

    h8 af[4], bf[4];
    const int rr = lane & 15;
    const int kk = (lane >> 4) * 8;
#pragma unroll
    for (int i = 0; i < 4; ++i)
      af[i] = *(const h8*)(As + (wm * 64 + i * 16 + rr) * 32 + kk);
#pragma unroll
    for (int j = 0; j < 4; ++j)
      bf[j] = *(const h8*)(Bs + (wn * 64 + j * 16 + rr) * 32 + kk);
#pragma unroll
    for (int i = 0; i < 4; ++i)
#pragma unroll
      for (int j = 0; j < 4; ++j)
        acc[i][j] = __builtin_amdgcn_mfma_f32_16x16x32_f16(af[i], bf[j], acc[i][j], 0, 0, 0);
  }

  const int r0 = bm * 128 + wm * 64;
  const int c0 = bn * 128 + wn * 64;
#pragma unroll
  for (int j = 0; j < 4; ++j) {
    int col = c0 + j * 16 + (lane & 15);
    float bc = bias[col];
#pragma unroll
    for (int i = 0; i < 4; ++i) {
#pragma unroll
      for (int jj = 0; jj < 4; ++jj) {
        int row = r0 + i * 16 + (lane >> 4) * 4 + jj;
        float val = acc[i][j][jj] + bc;
        if (EPI == 0) {
          int bb = row >> 11, s = row & (S_LEN - 1);
          int hh = col >> 6, dk = col & 63;
          if (blockIdx.z == 2) {
            ((half_t*)out)[((size_t)((bb * NHEAD + hh) * HDK + dk)) * S_LEN + s] = (half_t)val;
          } else {
            ((half_t*)out)[(((size_t)(bb * NHEAD + hh)) * S_LEN + s) * HDK + dk] =
                (half_t)(val * scale);
          }
        } else {
          ((float*)out)[(size_t)row * DMODEL + col] = val;
        }
      }
    }
  }
}

// ---------------------------------------------------------------------------
// Flash attention v3: swapped QK^T 32x32x16, K/V shared across the block's
// 4 waves via LDS double-buffer (global_load_lds, pre-swizzled source),
// cross-tile pipelined (STAGE t+1 before compute t), exp2 softmax with
// defer-max (THR=8 log2 units), setprio around MFMA clusters.
__global__ __launch_bounds__(256, 2) void attn_kernel(
    const half_t* __restrict__ Qp, const half_t* __restrict__ Kp,
    const half_t* __restrict__ VTp, const unsigned int* __restrict__ mbits,
    half_t* __restrict__ AO) {
  __shared__ half_t Ks[2][64 * 64];
  __shared__ half_t Vs[2][64 * 64];

  const int tid = threadIdx.x, w = tid >> 6, lane = tid & 63;
  // XCD-locality decode: 4 heads per XCD -> 2MB K/V working set per L2.
  const int id = blockIdx.x;
  const int xcd = id & 7, rr = id >> 3;
  const int qt = rr & 15;
  const int bh = (xcd << 2) | (rr >> 4);
  const int b = bh >> 4, h = bh & 15;
  const int q32 = lane & 31, hi = lane >> 5;
  const int qbase = qt * 128 + w * 32;
  const half_t* Qb = Qp + (size_t)bh * (S_LEN * HDK);
  const char* Kb = (const char*)(Kp + (size_t)bh * (S_LEN * HDK));
  const char* VTb = (const char*)(VTp + (size_t)bh * (S_LEN * HDK));
  const unsigned int* mrow = mbits + (size_t)(qbase + q32) * (S_LEN / 32);

  // per-lane staging constants
  const int srow = w * 16 + (lane >> 3);      // LDS row this lane fills (p=0)
  const int scb = (lane & 7) * 16;            // byte col within 128B row

  h8 qf[4];
#pragma unroll
  for (int s = 0; s < 4; ++s)
    qf[s] = *(const h8*)(Qb + (size_t)(qbase + q32) * HDK + s * 16 + hi * 8);

  f32x16 acc0 = {}, acc1 = {};
  float m_run = -1e30f, l_run = 0.f;

  // prologue: stage tile 0, load mask words for tile 0
  unsigned int mwA = mrow[0], mwB = mrow[1];
#pragma unroll
  for (int p = 0; p < 2; ++p) {
    int r = srow + p * 8;
    gload_lds16(Kb + (size_t)r * 128 + (scb ^ ((r & 7) << 4)),
                (char*)Ks[0] + (w * 16 + p * 8) * 128);
    gload_lds16(VTb + (size_t)r * (S_LEN * 2) + (scb ^ ((r & 7) << 4)),
                (char*)Vs[0] + (w * 16 + p * 8) * 128);
  }
  __syncthreads();

  int cur = 0;
  for (int kv = 0; kv < S_LEN / 64; ++kv) {
    const unsigned int mw0 = mwA >> (hi * 4);
    const unsigned int mw1 = mwB >> (hi * 4);

    // stage next tile into buf^1 (overlaps this tile's compute)
    if (kv < S_LEN / 64 - 1) {
#pragma unroll
      for (int p = 0; p < 2; ++p) {
        int r = srow + p * 8;
        gload_lds16(Kb + (size_t)((kv + 1) * 64 + r) * 128 + (scb ^ ((r & 7) << 4)),
                    (char*)Ks[cur ^ 1] + (w * 16 + p * 8) * 128);
        gload_lds16(VTb + (size_t)r * (S_LEN * 2) + (kv + 1) * 128 + (scb ^ ((r & 7) << 4)),
                    (char*)Vs[cur ^ 1] + (w * 16 + p * 8) * 128);
      }
      mwA = mrow[(kv + 1) * 2];
      mwB = mrow[(kv + 1) * 2 + 1];
    }

    // QK^T from LDS
    const char* kb = (const char*)Ks[cur];
    const char* vb = (const char*)Vs[cur];
    f32x16 sc0 = {}, sc1 = {};
    __builtin_amdgcn_s_setprio(1);
#pragma unroll
    for (int s = 0; s < 4; ++s) {
      h8 kf0 = *(const h8*)(kb + swz(q32, s * 32 + hi * 16));
      h8 kf1 = *(const h8*)(kb + swz(32 + q32, s * 32 + hi * 16));
      sc0 = __builtin_amdgcn_mfma_f32_32x32x16_f16(kf0, qf[s], sc0, 0, 0, 0);
      sc1 = __builtin_amdgcn_mfma_f32_32x32x16_f16(kf1, qf[s], sc1, 0, 0, 0);
    }
    __builtin_amdgcn_s_setprio(0);

    // V fragments (LDS latency hides under softmax)
    h8 vf0[4], vf1[4];
#pragma unroll
    for (int s = 0; s < 4; ++s) {
      vf0[s] = *(const h8*)(vb + swz(q32, s * 32 + hi * 16));
      vf1[s] = *(const h8*)(vb + swz(32 + q32, s * 32 + hi * 16));
    }

    // mask (-> 1e-9*log2e, scores are in log2 units) + row max
    float mx = -1e30f;
#pragma unroll
    for (int rg = 0; rg < 16; ++rg) {
      const int bit = (rg & 3) + 8 * (rg >> 2);
      float s0 = ((mw0 >> bit) & 1u) ? sc0[rg] : 1.44269504e-9f;
      float s1 = ((mw1 >> bit) & 1u) ? sc1[rg] : 1.44269504e-9f;
      sc0[rg] = s0; sc1[rg] = s1;
      mx = fmaxf(mx, fmaxf(s0, s1));
    }
    mx = fmaxf(mx, __shfl_xor(mx, 32));

    // defer-max: only rescale when the running max grew by > 8 (p <= 2^8)
    if (!__all(mx <= m_run + 8.0f)) {
      float mnew = fmaxf(m_run, mx);
      float scl = fast_exp2(m_run - mnew);
      l_run *= scl;
#pragma unroll
      for (int rg = 0; rg < 16; ++rg) { acc0[rg] *= scl; acc1[rg] *= scl; }
      m_run = mnew;
    }

    float rs = 0.f;
#pragma unroll
    for (int rg = 0; rg < 16; ++rg) {
      float p0 = fast_exp2(sc0[rg] - m_run);
      float p1 = fast_exp2(sc1[rg] - m_run);
      sc0[rg] = p0; sc1[rg] = p1;
      rs += p0 + p1;
    }
    rs += __shfl_xor(rs, 32);
    l_run += rs;

    // P (f32, lane-local P^T) -> f16 B-fragments via pack + permlane32_swap
    h8 pb[4];
#pragma unroll
    for (int s = 0; s < 4; ++s) {
      f32x16& P = (s < 2) ? sc0 : sc1;
      const int rb = (s & 1) * 8;
      union { h2 h; unsigned int u; } c01, c23, c45, c67;
      c01.h[0] = (half_t)P[rb + 0]; c01.h[1] = (half_t)P[rb + 1];
      c23.h[0] = (half_t)P[rb + 2]; c23.h[1] = (half_t)P[rb + 3];
      c45.h[0] = (half_t)P[rb + 4]; c45.h[1] = (half_t)P[rb + 5];
      c67.h[0] = (half_t)P[rb + 6]; c67.h[1] = (half_t)P[rb + 7];
      auto rA = __builtin_amdgcn_permlane32_swap(c01.u, c45.u, false, false);
      auto rB = __builtin_amdgcn_permlane32_swap(c23.u, c67.u, false, false);
      union { unsigned int u[4]; h8 v; } bw;
      bw.u[0] = rA[0]; bw.u[1] = rB[0]; bw.u[2] = rA[1]; bw.u[3] = rB[1];
      pb[s] = bw.v;
    }

    // PV: acc[d][q] += V^T . P
    __builtin_amdgcn_s_setprio(1);
#pragma unroll
    for (int s = 0; s < 4; ++s) {
      acc0 = __builtin_amdgcn_mfma_f32_32x32x16_f16(vf0[s], pb[s], acc0, 0, 0, 0);
      acc1 = __builtin_amdgcn_mfma_f32_32x32x16_f16(vf1[s], pb[s], acc1, 0, 0, 0);
    }
    __builtin_amdgcn_s_setprio(0);

    __syncthreads();  // next tile staged; all waves done reading buf
    cur ^= 1;
  }

  // epilogue: AO[b*S+q][h*64+d] = acc/l, packed 8B stores
  const float inv = 1.0f / l_run;
  const int qrow = qbase + q32;
  half_t* aob = AO + (size_t)(b * S_LEN + qrow) * DMODEL + h * HDK;
#pragma unroll
  for (int rq = 0; rq < 4; ++rq) {
    h4 s0, s1;
#pragma unroll
    for (int j = 0; j < 4; ++j) {
      s0[j] = (half_t)(acc0[rq * 4 + j] * inv);
      s1[j] = (half_t)(acc1[rq * 4 + j] * inv);
    }
    const int d0 = 8 * rq + 4 * hi;
    *(h4*)(aob + d0) = s0;
    *(h4*)(aob + 32 + d0) = s1;
  }
}

// ---------------------------------------------------------------------------
extern "C" void kernel_launch(void* const* d_in, const int* in_sizes, int n_in,
                              void* d_out, int out_size, void* d_ws, size_t ws_size,
                              hipStream_t stream) {
  const float* q    = (const float*)d_in[0];
  const float* k    = (const float*)d_in[1];
  const float* v    = (const float*)d_in[2];
  const int*   mask = (const int*)d_in[3];
  const float* wq_w = (const float*)d_in[4];
  const float* wq_b = (const float*)d_in[5];
  const float* wk_w = (const float*)d_in[6];
  const float* wk_b = (const float*)d_in[7];
  const float* wv_w = (const float*)d_in[8];
  const float* wv_b = (const float*)d_in[9];
  const float* wo_w = (const float*)d_in[10];
  const float* wo_b = (const float*)d_in[11];
  float* out = (float*)d_out;

  char* ws = (char*)d_ws;
  const size_t MB = (size_t)1 << 20;
  half_t* Xq = (half_t*)(ws + 0 * MB);
  half_t* Xk = (half_t*)(ws + 8 * MB);
  half_t* Xv = (half_t*)(ws + 16 * MB);
  half_t* Wq = (half_t*)(ws + 24 * MB);
  half_t* Wk = (half_t*)(ws + 26 * MB);
  half_t* Wv = (half_t*)(ws + 28 * MB);
  half_t* Wo = (half_t*)(ws + 30 * MB);
  half_t* Qp = (half_t*)(ws + 32 * MB);
  half_t* Kp = (half_t*)(ws + 40 * MB);
  half_t* VT = (half_t*)(ws + 48 * MB);
  unsigned int* mbits = (unsigned int*)(ws + 56 * MB);
  half_t* AO = Xq;  // Xq dead after projections

  pre_kernel<<<32768, 256, 0, stream>>>(q, k, v, wq_w, wk_w, wv_w, wo_w, mask,
                                        Xq, Xk, Xv, Wq, Wk, Wv, Wo, mbits);
  gemm_kernel<0><<<dim3(32, 8, 3), 256, 0, stream>>>(
      Xq, Xk, Xv, Wq, Wk, Wv, wq_b, wk_b, wv_b, (void*)Qp, (void*)Kp, (void*)VT);
  attn_kernel<<<512, 256, 0, stream>>>(Qp, Kp, VT, mbits, AO);
  gemm_kernel<1><<<dim3(32, 8, 1), 256, 0, stream>>>(
      AO, AO, AO, Wo, Wo, Wo, wo_b, wo_b, wo_b, (void*)out, (void*)out, (void*)out);

  (void)in_sizes; (void)n_in; (void)out_size; (void)ws_size;
}